// Round 6
// baseline (257.781 us; speedup 1.0000x reference)
//
#include <hip/hip_runtime.h>
#include <math.h>

#define K 3
#define K2 9
#define BB 4
#define C 64
#define H 128
#define W 128
#define O 64
#define HW (H*W)
#define Ho 128
#define Wo 128
#define TILE 64        // pixels per block (along w)
#define CG 16          // input channels per chunk
#define NCHUNK 4       // C / CG
#define KCH 144        // CG*K2 valid k per chunk
#define NSTEP 5        // ceil(KCH/32) K-steps of 32
#define SA_STRIDE 164  // halves per px row (328 B, 8B-aligned rows; known-good)

typedef _Float16 half4v __attribute__((ext_vector_type(4)));
typedef _Float16 half8v __attribute__((ext_vector_type(8)));
typedef float float4v __attribute__((ext_vector_type(4)));

__device__ __forceinline__ half8v load_frag_lds(const _Float16* p) {
    half4v a = *(const half4v*)p;        // 8B-aligned (row stride 328B, koff mult of 8)
    half4v b = *(const half4v*)(p + 4);
    return __builtin_shufflevector(a, b, 0, 1, 2, 3, 4, 5, 6, 7);
}

// ---------------------------------------------------------------------------
// conv_x16: one-time fp32 -> fp16 copy of x (halves scattered-gather bytes).
// Phase A already quantized x to fp16 in LDS in the passing round-4 kernel,
// so this adds no new error to the offset conv; gather corners gain <=1e-3.
// ---------------------------------------------------------------------------
__global__ void conv_x16(const float* __restrict__ x, _Float16* __restrict__ x16) {
    int i = blockIdx.x * blockDim.x + threadIdx.x;   // BB*C*HW/4 threads exactly
    float4v v = ((const float4v*)x)[i];
    half4v h;
    h[0] = (_Float16)v[0]; h[1] = (_Float16)v[1];
    h[2] = (_Float16)v[2]; h[3] = (_Float16)v[3];
    ((half4v*)x16)[i] = h;
}

// ---------------------------------------------------------------------------
// prep_weights: pack conv weights into MFMA B-fragment order, fp16.
//  wB  (main conv): [cc][s][q=o-tile(4)][lane(64)][jj(8)]
//       k = s*32+(lane>>4)*8+jj (k = cl*9+tap within chunk), o = q*16+(lane&15)
//  wAB (offset+mod): [cc][s][jt=n-tile(2)][lane(64)][jj(8)], n = jt*16+(lane&15)
// ---------------------------------------------------------------------------
__global__ void prep_weights(const float* __restrict__ weight,
                             const float* __restrict__ offset_w,
                             const float* __restrict__ mod_w,
                             _Float16* __restrict__ wB,
                             _Float16* __restrict__ wAB)
{
    int i = blockIdx.x * blockDim.x + threadIdx.x;
    if (i < NCHUNK * NSTEP * 4 * 64 * 8) {          // 40960
        int jj = i & 7;
        int lane = (i >> 3) & 63;
        int q = (i >> 9) & 3;
        int i2 = i >> 11;
        int cc = i2 / NSTEP, s = i2 % NSTEP;
        int k = s * 32 + ((lane >> 4) & 3) * 8 + jj;
        int o = q * 16 + (lane & 15);
        float wv = 0.f;
        if (k < KCH) {
            int c = cc * CG + k / 9;
            int tap = k % 9;
            wv = weight[(o * C + c) * 9 + tap];
        }
        wB[i] = (_Float16)wv;
    }
    if (i < NCHUNK * NSTEP * 2 * 64 * 8) {          // 20480
        int jj = i & 7;
        int lane = (i >> 3) & 63;
        int jt = (i >> 9) & 1;
        int i2 = i >> 10;
        int cc = i2 / NSTEP, s = i2 % NSTEP;
        int k = s * 32 + ((lane >> 4) & 3) * 8 + jj;
        int n = jt * 16 + (lane & 15);
        float wv = 0.f;
        if (k < KCH && n < 27) {
            int c = cc * CG + k / 9;
            int tap = k % 9;
            wv = (n < 18) ? offset_w[(n * C + c) * 9 + tap]
                          : mod_w[((n - 18) * C + c) * 9 + tap];
        }
        wAB[i] = (_Float16)wv;
    }
}

// ---------------------------------------------------------------------------
// fused_kernel: one block per (b,h,64px strip), 256 threads, 4 waves.
// ROUND-4 VERBATIM structure (known-correct phase B/C encoding:
// clamped corner addrs + dx/dy bits + mask-folded AXIS weights),
// templated on x dtype; plain __launch_bounds__(256) (no spill).
// ---------------------------------------------------------------------------
template <typename XT>
__global__ __launch_bounds__(256) void fused_kernel(
    const XT* __restrict__ x,
    const _Float16* __restrict__ wB,
    const _Float16* __restrict__ wAB,
    const float* __restrict__ bias,
    const float* __restrict__ offset_b,
    const float* __restrict__ mod_b,
    float* __restrict__ out)
{
    __shared__ _Float16 s_A[TILE][SA_STRIDE];   // 20,992 B (A-frags; out overlay)
    __shared__ unsigned int s_ai[K2 * TILE];    //  2,304 B (a00 | dx<<14 | dy<<15)
    __shared__ float4v s_wgt[K2 * TILE];        //  9,216 B (wy0,wy1,wx0,wx1)
    __shared__ float s_res[27 * 65];            //  7,020 B (offset/mod conv result)
    __shared__ float s_mm[TILE];                //    256 B
    float* s_out = (float*)&s_A[0][0];          // overlay [64][65] after phase C

    int blk = blockIdx.x;
    int wt = blk % (Wo / TILE);
    int h  = (blk / (Wo / TILE)) % Ho;
    int b  = blk / ((Wo / TILE) * Ho);
    int t  = threadIdx.x;
    int px = t & 63;
    int q  = t >> 6;
    int lane = t & 63;
    int m16 = lane & 15;
    int quad = (lane >> 4) & 3;
    int w0 = wt * TILE;
    int wp = w0 + px;

    // zero k-pad rows 144..159 (persist across both MFMA phases)
    for (int z = t; z < TILE * 16; z += 256)
        s_A[z >> 4][KCH + (z & 15)] = (_Float16)0.f;

    // patch geometry (regs, reused across phase-A chunks)
    int yy[3]; float ymask[3];
    int xx[3]; float xmask[3];
    #pragma unroll
    for (int i = 0; i < 3; i++) {
        int y = h + i - 1;
        ymask[i] = (y >= 0 && y < H) ? 1.f : 0.f;
        yy[i] = min(max(y, 0), H - 1);
        int xv = wp + i - 1;
        xmask[i] = (xv >= 0 && xv < W) ? 1.f : 0.f;
        xx[i] = min(max(xv, 0), W - 1);
    }

    const XT* xb = x + (size_t)b * C * HW;

    // ================= phase A: offset/mod conv =================
    float4v acc2[2];
    #pragma unroll
    for (int jt = 0; jt < 2; jt++) { float4v z = {0.f,0.f,0.f,0.f}; acc2[jt] = z; }

    #pragma unroll 1
    for (int cc = 0; cc < NCHUNK; cc++) {
        __syncthreads();
        #pragma unroll
        for (int mi = 0; mi < 4; mi++) {
            int cl = q * 4 + mi;
            const XT* xc = xb + (size_t)(cc * CG + cl) * HW;
            #pragma unroll
            for (int ti = 0; ti < 3; ti++) {
                #pragma unroll
                for (int tj = 0; tj < 3; tj++) {
                    float v = (float)xc[yy[ti] * W + xx[tj]] * (ymask[ti] * xmask[tj]);
                    s_A[px][cl * 9 + ti * 3 + tj] = (_Float16)v;
                }
            }
        }
        __syncthreads();

        int row = q * 16 + m16;
        #pragma unroll
        for (int s = 0; s < NSTEP; s++) {
            int koff = s * 32 + quad * 8;
            half8v af = load_frag_lds(&s_A[row][koff]);
            #pragma unroll
            for (int jt = 0; jt < 2; jt++) {
                int idx = (((cc * NSTEP + s) * 2 + jt) * 64 + lane) * 8;
                half8v bf = *(const half8v*)(wAB + idx);
                acc2[jt] = __builtin_amdgcn_mfma_f32_16x16x32_f16(af, bf, acc2[jt], 0, 0, 0);
            }
        }
    }
    __syncthreads();
    // C layout: col(n)=lane&15, row(px-in-tile)=quad*4+reg; wave q owns px-tile q
    #pragma unroll
    for (int jt = 0; jt < 2; jt++) {
        int n = jt * 16 + m16;
        if (n < 27) {
            #pragma unroll
            for (int r = 0; r < 4; r++)
                s_res[n * 65 + q * 16 + quad * 4 + r] = acc2[jt][r];
        }
    }
    __syncthreads();

    // ================= phase B: bilinear params + modmean (round-4 verbatim) ==
    #pragma unroll
    for (int ee = 0; ee < 3; ee++) {
        int e = t + ee * 256;
        if (e < K2 * TILE) {
            int k = e >> 6, p = e & 63;
            float offy = s_res[k * 65 + p] + offset_b[k];
            float offx = s_res[(9 + k) * 65 + p] + offset_b[9 + k];
            float sy = (float)(h + k / 3 - 1) + offy;
            float sx = (float)(w0 + p + k % 3 - 1) + offx;
            float fy = floorf(sy), fx = floorf(sx);
            int y0 = (int)fy, x0 = (int)fx;
            float wy1 = sy - fy, wx1 = sx - fx;
            int y0c = min(max(y0, 0), H - 1), y1c = min(max(y0 + 1, 0), H - 1);
            int x0c = min(max(x0, 0), W - 1), x1c = min(max(x0 + 1, 0), W - 1);
            s_ai[e] = (unsigned int)(y0c * W + x0c)
                    | ((unsigned int)(x1c - x0c) << 14)
                    | ((unsigned int)(y1c - y0c) << 15);
            float4v wg;
            wg[0] = (1.f - wy1) * ((y0 >= 0 && y0 < H) ? 1.f : 0.f);
            wg[1] = wy1 * ((y0 + 1 >= 0 && y0 + 1 < H) ? 1.f : 0.f);
            wg[2] = (1.f - wx1) * ((x0 >= 0 && x0 < W) ? 1.f : 0.f);
            wg[3] = wx1 * ((x0 + 1 >= 0 && x0 + 1 < W) ? 1.f : 0.f);
            s_wgt[e] = wg;
        }
    }
    if (t < TILE) {
        float sm = 0.f;
        #pragma unroll
        for (int m = 0; m < 9; m++) {
            float z = s_res[(18 + m) * 65 + t] + mod_b[m];
            sm += 1.f / (1.f + expf(-z));
        }
        s_mm[t] = sm * (1.f / 9.f);
    }

    // ================= phase C: gather + main MFMA =================
    float4v acc[4];
    #pragma unroll
    for (int i = 0; i < 4; i++) { float4v z = {0.f,0.f,0.f,0.f}; acc[i] = z; }

    #pragma unroll 1
    for (int cc = 0; cc < NCHUNK; cc++) {
        __syncthreads();
        #pragma unroll
        for (int j = 0; j < K2; j++) {
            int e = j * 64 + px;
            unsigned int ai = s_ai[e];
            float4v wg = s_wgt[e];
            int a00 = ai & 0x3FFF;
            int dx  = (ai >> 14) & 1;
            int dyW = ((ai >> 15) & 1) * W;
            #pragma unroll
            for (int mi = 0; mi < 4; mi++) {
                int cl = q * 4 + mi;
                const XT* xc = xb + (size_t)(cc * CG + cl) * HW;
                float v00 = (float)xc[a00];
                float v01 = (float)xc[a00 + dx];
                float v10 = (float)xc[a00 + dyW];
                float v11 = (float)xc[a00 + dyW + dx];
                float v = wg[0] * (v00 * wg[2] + v01 * wg[3])
                        + wg[1] * (v10 * wg[2] + v11 * wg[3]);
                s_A[px][cl * 9 + j] = (_Float16)v;
            }
        }
        __syncthreads();

        // wave q owns o-tile q; px-tiles i = 0..3
        #pragma unroll
        for (int s = 0; s < NSTEP; s++) {
            int idx = (((cc * NSTEP + s) * 4 + q) * 64 + lane) * 8;
            half8v bf = *(const half8v*)(wB + idx);
            int koff = s * 32 + quad * 8;
            #pragma unroll
            for (int i = 0; i < 4; i++) {
                half8v af = load_frag_lds(&s_A[i * 16 + m16][koff]);
                acc[i] = __builtin_amdgcn_mfma_f32_16x16x32_f16(af, bf, acc[i], 0, 0, 0);
            }
        }
    }

    // ================= epilogue =================
    __syncthreads();
    #pragma unroll
    for (int i = 0; i < 4; i++) {
        int o = q * 16 + m16;
        #pragma unroll
        for (int r = 0; r < 4; r++)
            s_out[o * 65 + i * 16 + quad * 4 + r] = acc[i][r];
    }
    __syncthreads();
    {
        float mm = s_mm[px];
        #pragma unroll
        for (int jj = 0; jj < 16; jj++) {
            int o = q * 16 + jj;
            out[(((size_t)b * O + o) * Ho + h) * Wo + w0 + px] =
                s_out[o * 65 + px] * mm + bias[o];
        }
    }
}

extern "C" void kernel_launch(void* const* d_in, const int* in_sizes, int n_in,
                              void* d_out, int out_size, void* d_ws, size_t ws_size,
                              hipStream_t stream) {
    const float* x        = (const float*)d_in[0];
    const float* weight   = (const float*)d_in[1];
    const float* bias     = (const float*)d_in[2];
    const float* offset_w = (const float*)d_in[3];
    const float* offset_b = (const float*)d_in[4];
    const float* mod_w    = (const float*)d_in[5];
    const float* mod_b    = (const float*)d_in[6];
    float* out = (float*)d_out;

    // Workspace layout (bytes): wB 81,920 | wAB 40,960 | x16 8,388,608
    _Float16* wB  = (_Float16*)d_ws;            // 40960 halves
    _Float16* wAB = wB + 40960;                 // 20480 halves
    _Float16* x16 = wAB + 20480;                // byte offset 122,880 (16B-aligned)
    size_t need = 122880 + (size_t)BB * C * HW * sizeof(_Float16);

    prep_weights<<<160, 256, 0, stream>>>(weight, offset_w, mod_w, wB, wAB);

    int nblk = BB * Ho * (Wo / TILE);   // 1024
    if (ws_size >= need) {
        conv_x16<<<BB * C * HW / 4 / 256, 256, 0, stream>>>(x, x16);
        fused_kernel<_Float16><<<nblk, 256, 0, stream>>>(
            x16, wB, wAB, bias, offset_b, mod_b, out);
    } else {
        fused_kernel<float><<<nblk, 256, 0, stream>>>(
            x, wB, wAB, bias, offset_b, mod_b, out);
    }
}

// Round 7
// 134.787 us; speedup vs baseline: 1.9125x; 1.9125x over previous
//
#include <hip/hip_runtime.h>
#include <math.h>

#define K 3
#define K2 9
#define BB 4
#define C 64
#define H 128
#define W 128
#define O 64
#define HW (H*W)
#define Ho 128
#define Wo 128
#define TILE 64        // pixels per block (along w)
#define CG 16          // input channels per chunk
#define NCHUNK 4       // C / CG
#define KCH 144        // CG*K2 valid k per chunk (tap-major: k = tap*16 + cl)
#define NSTEP 5        // ceil(KCH/32) K-steps of 32
#define SA_STRIDE 164  // halves per px row (328 B = 82 dwords, 82%32=18 -> <=4-way)

typedef _Float16 half4v __attribute__((ext_vector_type(4)));
typedef _Float16 half8v __attribute__((ext_vector_type(8)));
typedef float float4v __attribute__((ext_vector_type(4)));

__device__ __forceinline__ half8v load_frag_lds(const _Float16* p) {
    half4v a = *(const half4v*)p;        // 8B-aligned (row stride 328B, koff mult of 8)
    half4v b = *(const half4v*)(p + 4);
    return __builtin_shufflevector(a, b, 0, 1, 2, 3, 4, 5, 6, 7);
}
__device__ __forceinline__ void store16_lds(_Float16* d, half8v v) {
    *(half4v*)d       = __builtin_shufflevector(v, v, 0, 1, 2, 3);
    *(half4v*)(d + 4) = __builtin_shufflevector(v, v, 4, 5, 6, 7);
}

// ---------------------------------------------------------------------------
// make_xh: NCHW fp32 -> NHWC fp16 (xh[b][y][x][c], 128 B per pixel record).
// One block per (b,y) row; LDS tile transpose; coalesced in and out.
// ---------------------------------------------------------------------------
__global__ __launch_bounds__(256) void make_xh(const float* __restrict__ x,
                                               _Float16* __restrict__ xh)
{
    __shared__ _Float16 tile[W][68];     // x-pos x channel (pad 68)
    int by = blockIdx.x;                 // 0..BB*H-1
    int y = by % H, b = by / H;
    int t = threadIdx.x;
    int xp = t & 127, ch0 = t >> 7;      // 0/1
    for (int g = 0; g < 32; g++) {
        int c = g * 2 + ch0;
        tile[xp][c] = (_Float16)x[(((size_t)b * C + c) * H + y) * W + xp];
    }
    __syncthreads();
    int xp2 = t >> 1, hf = t & 1;        // each thread writes 32 ch = 64 B
    const _Float16* src = &tile[xp2][hf * 32];
    _Float16* dst = xh + (((size_t)b * H + y) * W + xp2) * 64 + hf * 32;
    #pragma unroll
    for (int i = 0; i < 8; i++)
        *(half4v*)(dst + i * 4) = *(const half4v*)(src + i * 4);
}

// ---------------------------------------------------------------------------
// prep_weights: pack conv weights into MFMA B-fragment order, fp16,
// TAP-MAJOR k within chunk: k = tap*16 + cl, c = cc*16 + cl.
//  wB : [cc][s][q=o-tile(4)][lane(64)][jj(8)]
//  wAB: [cc][s][jt=n-tile(2)][lane(64)][jj(8)], n = jt*16+(lane&15) in 0..26
// ---------------------------------------------------------------------------
__global__ void prep_weights(const float* __restrict__ weight,
                             const float* __restrict__ offset_w,
                             const float* __restrict__ mod_w,
                             _Float16* __restrict__ wB,
                             _Float16* __restrict__ wAB)
{
    int i = blockIdx.x * blockDim.x + threadIdx.x;
    if (i < NCHUNK * NSTEP * 4 * 64 * 8) {          // 40960
        int jj = i & 7;
        int lane = (i >> 3) & 63;
        int q = (i >> 9) & 3;
        int i2 = i >> 11;
        int cc = i2 / NSTEP, s = i2 % NSTEP;
        int k = s * 32 + ((lane >> 4) & 3) * 8 + jj;
        int o = q * 16 + (lane & 15);
        float wv = 0.f;
        if (k < KCH) {
            int tap = k >> 4, cl = k & 15;
            int c = cc * CG + cl;
            wv = weight[(o * C + c) * 9 + tap];
        }
        wB[i] = (_Float16)wv;
    }
    if (i < NCHUNK * NSTEP * 2 * 64 * 8) {          // 20480
        int jj = i & 7;
        int lane = (i >> 3) & 63;
        int jt = (i >> 9) & 1;
        int i2 = i >> 10;
        int cc = i2 / NSTEP, s = i2 % NSTEP;
        int k = s * 32 + ((lane >> 4) & 3) * 8 + jj;
        int n = jt * 16 + (lane & 15);
        float wv = 0.f;
        if (k < KCH && n < 27) {
            int tap = k >> 4, cl = k & 15;
            int c = cc * CG + cl;
            wv = (n < 18) ? offset_w[(n * C + c) * 9 + tap]
                          : mod_w[((n - 18) * C + c) * 9 + tap];
        }
        wAB[i] = (_Float16)wv;
    }
}

// ---------------------------------------------------------------------------
// fused_kernel: one block per (b,h,64px strip), 256 threads, 4 waves.
// Wave q owns taps {2q, 2q+1} (+ tap 8 for q==0) -> wave-uniform split.
// All gathers are 16B dwordx4 loads from HWC xh; bilinear in packed fp16.
// ---------------------------------------------------------------------------
__global__ __launch_bounds__(256) void fused_kernel(
    const _Float16* __restrict__ xh,
    const _Float16* __restrict__ wB,
    const _Float16* __restrict__ wAB,
    const float* __restrict__ bias,
    const float* __restrict__ offset_b,
    const float* __restrict__ mod_b,
    float* __restrict__ out)
{
    __shared__ _Float16 s_A[TILE][SA_STRIDE];   // 20,992 B (A-frags; out overlay)
    __shared__ unsigned int s_ai[K2 * TILE];    //  2,304 B (a00 | dx<<14 | dy<<15)
    __shared__ float4v s_wgt[K2 * TILE];        //  9,216 B (wy0,wy1,wx0,wx1)
    __shared__ float s_res[27 * 65];            //  7,020 B (offset/mod conv result)
    __shared__ float s_mm[TILE];                //    256 B
    float* s_out = (float*)&s_A[0][0];          // overlay [64][65] after phase C

    // XCD-aware swizzle: xcd = blk&7 (round-robin heuristic); each XCD gets a
    // contiguous 64-row h-band of one batch image (~1 MB working set < 4 MB L2).
    int blk = blockIdx.x;
    int xcd = blk & 7, idx = blk >> 3;          // idx in [0,128)
    int b  = xcd >> 1;
    int h  = ((xcd & 1) << 6) | (idx >> 1);
    int wt = idx & 1;
    int t  = threadIdx.x;
    int px = t & 63;
    int q  = t >> 6;                            // wave index (uniform per wave)
    int lane = t & 63;
    int m16 = lane & 15;
    int quad = (lane >> 4) & 3;
    int w0 = wt * TILE;
    int wp = w0 + px;

    // zero k-pad rows 144..159
    for (int z = t; z < TILE * 16; z += 256)
        s_A[z >> 4][KCH + (z & 15)] = (_Float16)0.f;

    const _Float16* xb = xh + (size_t)b * HW * 64;

    // ================= phase A: offset/mod conv =================
    float4v acc2[2];
    #pragma unroll
    for (int jt = 0; jt < 2; jt++) { float4v z = {0.f,0.f,0.f,0.f}; acc2[jt] = z; }

    #pragma unroll 1
    for (int cc = 0; cc < NCHUNK; cc++) {
        __syncthreads();
        #pragma unroll
        for (int ti = 0; ti < 3; ti++) {
            if (ti == 2 && q != 0) break;            // wave-uniform
            int tap = (ti < 2) ? (2 * q + ti) : 8;
            int ki = tap / 3, kj = tap % 3;
            int y = h + ki - 1;
            int xv = wp + kj - 1;
            float m = ((y >= 0 && y < H) ? 1.f : 0.f) * ((xv >= 0 && xv < W) ? 1.f : 0.f);
            int yc = min(max(y, 0), H - 1), xcl = min(max(xv, 0), W - 1);
            const _Float16* src = xb + ((size_t)yc * W + xcl) * 64 + cc * CG;
            half8v v0 = *(const half8v*)src;
            half8v v1 = *(const half8v*)(src + 8);
            _Float16 mh = (_Float16)m;
            half8v vm = {mh, mh, mh, mh, mh, mh, mh, mh};
            v0 *= vm; v1 *= vm;
            _Float16* d = &s_A[px][tap * 16];
            store16_lds(d, v0);
            store16_lds(d + 8, v1);
        }
        __syncthreads();

        int row = q * 16 + m16;
        #pragma unroll
        for (int s = 0; s < NSTEP; s++) {
            int koff = s * 32 + quad * 8;
            half8v af = load_frag_lds(&s_A[row][koff]);
            #pragma unroll
            for (int jt = 0; jt < 2; jt++) {
                int widx = (((cc * NSTEP + s) * 2 + jt) * 64 + lane) * 8;
                half8v bf = *(const half8v*)(wAB + widx);
                acc2[jt] = __builtin_amdgcn_mfma_f32_16x16x32_f16(af, bf, acc2[jt], 0, 0, 0);
            }
        }
    }
    __syncthreads();
    // C layout: col(n)=lane&15, row(px-in-tile)=quad*4+reg; wave q owns px-tile q
    #pragma unroll
    for (int jt = 0; jt < 2; jt++) {
        int n = jt * 16 + m16;
        if (n < 27) {
            #pragma unroll
            for (int r = 0; r < 4; r++)
                s_res[n * 65 + q * 16 + quad * 4 + r] = acc2[jt][r];
        }
    }
    __syncthreads();

    // ================= phase B: bilinear params + modmean (round-6 verbatim) ==
    #pragma unroll
    for (int ee = 0; ee < 3; ee++) {
        int e = t + ee * 256;
        if (e < K2 * TILE) {
            int k = e >> 6, p = e & 63;
            float offy = s_res[k * 65 + p] + offset_b[k];
            float offx = s_res[(9 + k) * 65 + p] + offset_b[9 + k];
            float sy = (float)(h + k / 3 - 1) + offy;
            float sx = (float)(w0 + p + k % 3 - 1) + offx;
            float fy = floorf(sy), fx = floorf(sx);
            int y0 = (int)fy, x0 = (int)fx;
            float wy1 = sy - fy, wx1 = sx - fx;
            int y0c = min(max(y0, 0), H - 1), y1c = min(max(y0 + 1, 0), H - 1);
            int x0c = min(max(x0, 0), W - 1), x1c = min(max(x0 + 1, 0), W - 1);
            s_ai[e] = (unsigned int)(y0c * W + x0c)
                    | ((unsigned int)(x1c - x0c) << 14)
                    | ((unsigned int)(y1c - y0c) << 15);
            float4v wg;
            wg[0] = (1.f - wy1) * ((y0 >= 0 && y0 < H) ? 1.f : 0.f);
            wg[1] = wy1 * ((y0 + 1 >= 0 && y0 + 1 < H) ? 1.f : 0.f);
            wg[2] = (1.f - wx1) * ((x0 >= 0 && x0 < W) ? 1.f : 0.f);
            wg[3] = wx1 * ((x0 + 1 >= 0 && x0 + 1 < W) ? 1.f : 0.f);
            s_wgt[e] = wg;
        }
    }
    if (t < TILE) {
        float sm = 0.f;
        #pragma unroll
        for (int m = 0; m < 9; m++) {
            float z = s_res[(18 + m) * 65 + t] + mod_b[m];
            sm += 1.f / (1.f + expf(-z));
        }
        s_mm[t] = sm * (1.f / 9.f);
    }

    // ================= phase C: gather + main MFMA =================
    float4v acc[4];
    #pragma unroll
    for (int i = 0; i < 4; i++) { float4v z = {0.f,0.f,0.f,0.f}; acc[i] = z; }

    #pragma unroll 1
    for (int cc = 0; cc < NCHUNK; cc++) {
        __syncthreads();
        #pragma unroll
        for (int ti = 0; ti < 3; ti++) {
            if (ti == 2 && q != 0) break;            // wave-uniform
            int tap = (ti < 2) ? (2 * q + ti) : 8;
            int e = tap * 64 + px;
            unsigned int ai = s_ai[e];
            float4v wg = s_wgt[e];
            float w00f = wg[0] * wg[2], w01f = wg[0] * wg[3];
            float w10f = wg[1] * wg[2], w11f = wg[1] * wg[3];
            int a00 = ai & 0x3FFF;
            int dxo = ((ai >> 14) & 1) * 64;
            int dyo = ((ai >> 15) & 1) * (W * 64);
            const _Float16* base = xb + (size_t)a00 * 64 + cc * CG;
            half8v r00a = *(const half8v*)(base);
            half8v r00b = *(const half8v*)(base + 8);
            half8v r01a = *(const half8v*)(base + dxo);
            half8v r01b = *(const half8v*)(base + dxo + 8);
            half8v r10a = *(const half8v*)(base + dyo);
            half8v r10b = *(const half8v*)(base + dyo + 8);
            half8v r11a = *(const half8v*)(base + dyo + dxo);
            half8v r11b = *(const half8v*)(base + dyo + dxo + 8);
            _Float16 w00 = (_Float16)w00f, w01 = (_Float16)w01f;
            _Float16 w10 = (_Float16)w10f, w11 = (_Float16)w11f;
            half8v vw00 = {w00,w00,w00,w00,w00,w00,w00,w00};
            half8v vw01 = {w01,w01,w01,w01,w01,w01,w01,w01};
            half8v vw10 = {w10,w10,w10,w10,w10,w10,w10,w10};
            half8v vw11 = {w11,w11,w11,w11,w11,w11,w11,w11};
            half8v va = r00a * vw00 + r01a * vw01 + r10a * vw10 + r11a * vw11;
            half8v vb = r00b * vw00 + r01b * vw01 + r10b * vw10 + r11b * vw11;
            _Float16* d = &s_A[px][tap * 16];
            store16_lds(d, va);
            store16_lds(d + 8, vb);
        }
        __syncthreads();

        // wave q owns o-tile q; px-tiles i = 0..3
        #pragma unroll
        for (int s = 0; s < NSTEP; s++) {
            int widx = (((cc * NSTEP + s) * 4 + q) * 64 + lane) * 8;
            half8v bf = *(const half8v*)(wB + widx);
            int koff = s * 32 + quad * 8;
            #pragma unroll
            for (int i = 0; i < 4; i++) {
                half8v af = load_frag_lds(&s_A[i * 16 + m16][koff]);
                acc[i] = __builtin_amdgcn_mfma_f32_16x16x32_f16(af, bf, acc[i], 0, 0, 0);
            }
        }
    }

    // ================= epilogue =================
    __syncthreads();
    #pragma unroll
    for (int i = 0; i < 4; i++) {
        int o = q * 16 + m16;
        #pragma unroll
        for (int r = 0; r < 4; r++)
            s_out[o * 65 + i * 16 + quad * 4 + r] = acc[i][r];
    }
    __syncthreads();
    {
        float mm = s_mm[px];
        #pragma unroll
        for (int jj = 0; jj < 16; jj++) {
            int o = q * 16 + jj;
            out[(((size_t)b * O + o) * Ho + h) * Wo + w0 + px] =
                s_out[o * 65 + px] * mm + bias[o];
        }
    }
}

extern "C" void kernel_launch(void* const* d_in, const int* in_sizes, int n_in,
                              void* d_out, int out_size, void* d_ws, size_t ws_size,
                              hipStream_t stream) {
    const float* x        = (const float*)d_in[0];
    const float* weight   = (const float*)d_in[1];
    const float* bias     = (const float*)d_in[2];
    const float* offset_w = (const float*)d_in[3];
    const float* offset_b = (const float*)d_in[4];
    const float* mod_w    = (const float*)d_in[5];
    const float* mod_b    = (const float*)d_in[6];
    float* out = (float*)d_out;

    // Workspace (bytes): wB 81,920 | wAB 40,960 | xh 8,388,608 (16B-aligned)
    _Float16* wB  = (_Float16*)d_ws;            // 40960 halves
    _Float16* wAB = wB + 40960;                 // 20480 halves
    _Float16* xh  = wAB + 20480;                // byte offset 122,880

    prep_weights<<<160, 256, 0, stream>>>(weight, offset_w, mod_w, wB, wAB);
    make_xh<<<BB * H, 256, 0, stream>>>(x, xh);

    int nblk = BB * Ho * (Wo / TILE);   // 1024
    fused_kernel<<<nblk, 256, 0, stream>>>(
        xh, wB, wAB, bias, offset_b, mod_b, out);
}